// Round 11
// baseline (253.835 us; speedup 1.0000x reference)
//
#include <hip/hip_runtime.h>
#include <hip/hip_bf16.h>

#define N_NODES 50000
#define N_EDGES 1600000
#define IN_F 256
#define OUT_C 256   // OUT_F * NHEAD
#define NHEAD 4
#define HEAD_F 64
#define LRELU_ALPHA 0.2f

#define SCAN_BS 512
#define SCAN_NB ((N_NODES + SCAN_BS - 1) / SCAN_BS)   // 98

typedef __attribute__((ext_vector_type(8))) _Float16 f16x8;
typedef __attribute__((ext_vector_type(4))) float f32x4;

// ---------------- W pre-convert: f32 [K][N] -> chunked f16 ----------------
__global__ __launch_bounds__(256) void k_convw(const float* __restrict__ Wm,
                                               _Float16* __restrict__ Wh) {
    int t = blockIdx.x * 256 + threadIdx.x;   // t == k*256+n
    int k = t >> 8, n = t & 255;
    Wh[((k >> 3) * 256 + n) * 8 + (k & 7)] = (_Float16)Wm[t];
}

// ---------------- fused GEMM + ranked histogram (INTERLEAVED 1:16) ----------------
// b%17==0 -> gemm block g=b/17 (391 blocks); else hist block e_blk=b-b/17-1
// (6250 blocks). Interleaving starts the atomic drain at t=0 so it fully
// overlaps gemm instead of trailing it.
#define BM 128
#define BK 32
#define GEMM_NB ((N_NODES + BM - 1) / BM)        // 391
#define HIST_NB ((N_EDGES + 255) / 256)          // 6250
__global__ __launch_bounds__(256, 2) void k_gemm_hist(const float* __restrict__ x,
                                                      const _Float16* __restrict__ Wh,
                                                      const float* __restrict__ a_l,
                                                      const float* __restrict__ a_r,
                                                      _Float16* __restrict__ h16,
                                                      float* __restrict__ al_out,
                                                      float* __restrict__ ar_out,
                                                      const int* __restrict__ ei,
                                                      int* __restrict__ deg,
                                                      int* __restrict__ rank) {
    __shared__ _Float16 Ah[4 * 128 * 8];    // [kk][row][8]  8 KB
    __shared__ _Float16 Bh[4 * 256 * 8];    // [kk][col][8] 16 KB
    __shared__ float s_al[256], s_ar[256];

    const int b = blockIdx.x;
    const int g = b / 17;
    if ((b % 17) != 0) {
        int e = (b - g - 1) * 256 + threadIdx.x;
        if (e < N_EDGES) rank[e] = atomicAdd(&deg[ei[e]], 1);
        return;
    }

    const int t = threadIdx.x;
    const int w = t >> 6;
    const int l = t & 63;
    const int row0 = g * BM;

    s_al[t] = a_l[t];
    s_ar[t] = a_r[t];

    f32x4 acc0[16], acc1[16];
#pragma unroll
    for (int c = 0; c < 16; ++c) { acc0[c] = (f32x4)(0.f); acc1[c] = (f32x4)(0.f); }

    const int kk_r = l >> 4;
    const int li   = l & 15;

    for (int ks = 0; ks < 8; ++ks) {
        const int k0 = ks * BK;
        __syncthreads();
        // ---- stage A: 512 chunks (kk 0..3 x row 0..127); thread t does q=t, t+256
#pragma unroll
        for (int s = 0; s < 2; ++s) {
            int q = t + s * 256;
            int kk = q & 3, row = q >> 2;
            int grow = row0 + row;
            float4 v0 = make_float4(0.f, 0.f, 0.f, 0.f);
            float4 v1 = make_float4(0.f, 0.f, 0.f, 0.f);
            if (grow < N_NODES) {
                const float* src = &x[(size_t)grow * IN_F + k0 + kk * 8];
                v0 = *(const float4*)src;
                v1 = *(const float4*)(src + 4);
            }
            float f[8] = {v0.x, v0.y, v0.z, v0.w, v1.x, v1.y, v1.z, v1.w};
            f16x8 vh;
#pragma unroll
            for (int jj = 0; jj < 8; ++jj) vh[jj] = (_Float16)f[jj];
            *(f16x8*)&Ah[(kk * 128 + row) * 8] = vh;
        }
        // ---- stage B: 1024 chunks; thread t does q = t + s*256, s<4
        {
            const size_t tb = (size_t)(k0 >> 3) * 256 * 8;
#pragma unroll
            for (int s = 0; s < 4; ++s) {
                int q = s * 256 + t;
                *(f16x8*)&Bh[q * 8] = *(const f16x8*)&Wh[tb + (size_t)q * 8];
            }
        }
        __syncthreads();
        f16x8 a0 = *(f16x8*)&Ah[(kk_r * 128 + w * 16 + li) * 8];
        f16x8 a1 = *(f16x8*)&Ah[(kk_r * 128 + (w + 4) * 16 + li) * 8];
#pragma unroll
        for (int c = 0; c < 16; ++c) {
            f16x8 bh = *(f16x8*)&Bh[(kk_r * 256 + c * 16 + li) * 8];
            acc0[c] = __builtin_amdgcn_mfma_f32_16x16x32_f16(a0, bh, acc0[c], 0, 0, 0);
            acc1[c] = __builtin_amdgcn_mfma_f32_16x16x32_f16(a1, bh, acc1[c], 0, 0, 0);
        }
    }

    // ---- epilogue per row-tile: C layout row=(l>>4)*4+j, col=c*16+li ----
#pragma unroll
    for (int rt = 0; rt < 2; ++rt) {
        const int rbase = row0 + (w + rt * 4) * 16 + ((l >> 4) << 2);
#pragma unroll
        for (int c = 0; c < 16; ++c) {
#pragma unroll
            for (int j = 0; j < 4; ++j) {
                int row = rbase + j;
                float v = rt ? acc1[c][j] : acc0[c][j];
                if (row < N_NODES)
                    h16[(size_t)row * OUT_C + c * 16 + li] = (_Float16)v;
            }
        }
        // fused al/ar: column c*16+li belongs to head c>>2 (compile-time per c).
        float plh[4][4], prh[4][4];   // [head][j]
#pragma unroll
        for (int hd = 0; hd < 4; ++hd)
#pragma unroll
            for (int j = 0; j < 4; ++j) { plh[hd][j] = 0.f; prh[hd][j] = 0.f; }
#pragma unroll
        for (int c = 0; c < 16; ++c) {
            float av = s_al[c * 16 + li];
            float bv = s_ar[c * 16 + li];
#pragma unroll
            for (int j = 0; j < 4; ++j) {
                float v = rt ? acc1[c][j] : acc0[c][j];
                plh[c >> 2][j] += av * v;
                prh[c >> 2][j] += bv * v;
            }
        }
#pragma unroll
        for (int hd = 0; hd < 4; ++hd)
#pragma unroll
            for (int j = 0; j < 4; ++j)
#pragma unroll
                for (int s = 1; s <= 8; s <<= 1) {
                    plh[hd][j] += __shfl_xor(plh[hd][j], s);
                    prh[hd][j] += __shfl_xor(prh[hd][j], s);
                }
        if (li == 0) {
#pragma unroll
            for (int j = 0; j < 4; ++j) {
                int row = rbase + j;
                if (row < N_NODES) {
#pragma unroll
                    for (int hd = 0; hd < 4; ++hd) {
                        al_out[row * NHEAD + hd] = plh[hd][j];
                        ar_out[row * NHEAD + hd] = prh[hd][j];
                    }
                }
            }
        }
    }
}

// ---------------- scanA: per-block inclusive scan of deg ----------------
__global__ __launch_bounds__(SCAN_BS) void k_scanA(const int* __restrict__ deg,
                                                   int* __restrict__ incl,
                                                   int* __restrict__ bsums) {
    __shared__ int sm[SCAN_BS];
    const int tid = threadIdx.x;
    const int i = blockIdx.x * SCAN_BS + tid;
    int v = (i < N_NODES) ? deg[i] : 0;
    sm[tid] = v;
    __syncthreads();
    for (int off = 1; off < SCAN_BS; off <<= 1) {
        int add = (tid >= off) ? sm[tid - off] : 0;
        __syncthreads();
        sm[tid] += add;
        __syncthreads();
    }
    if (i < N_NODES) incl[i] = sm[tid];
    if (tid == SCAN_BS - 1) bsums[blockIdx.x] = sm[tid];
}

// ---------------- scanB: each block redundantly scans bsums, writes offs chunk ----
__global__ __launch_bounds__(SCAN_BS) void k_scanB(const int* __restrict__ deg,
                                                   const int* __restrict__ incl,
                                                   const int* __restrict__ bsums,
                                                   int* __restrict__ offs) {
    __shared__ int sb[128];
    const int tid = threadIdx.x;
    const int bid = blockIdx.x;
    if (tid < 128) sb[tid] = (tid < SCAN_NB) ? bsums[tid] : 0;
    __syncthreads();
    for (int off = 1; off < 128; off <<= 1) {
        int add = (tid >= off && tid < 128) ? sb[tid - off] : 0;
        __syncthreads();
        if (tid < 128) sb[tid] += add;
        __syncthreads();
    }
    const int bo = (bid == 0) ? 0 : sb[bid - 1];   // exclusive block offset
    const int n = bid * SCAN_BS + tid;
    if (n < N_NODES) offs[n] = incl[n] - deg[n] + bo;
}

// ---------------- CSR scatter: row-range-confined pass (atomic-free) -------------
// Pass handles rows [rlo, rlo+12500): its csr writes land in one contiguous
// ~1.6 MB region that stays cache-resident, so each 64B line absorbs all its
// ~16 random 4B writes before writeback.
__global__ __launch_bounds__(256) void k_scatter(const int* __restrict__ ei,
                                                 const int* __restrict__ rank,
                                                 const int* __restrict__ offs,
                                                 int* __restrict__ csr_col,
                                                 int rlo) {
    int e = blockIdx.x * 256 + threadIdx.x;
    if (e < N_EDGES) {
        int r = ei[e];
        if ((unsigned)(r - rlo) < 12500u)
            csr_col[offs[r] + rank[e]] = ei[N_EDGES + e];
    }
}

// ---------------- per-row segment softmax + SpMM: ONE WAVE PER ROW ----------------
// 128 threads = 2 waves = 2 rows. Lane l: edge slot l>>5, feature block j=l&31
// (features 8j..8j+7, head j>>3). Per iter a wave consumes 2 edges:
// one 16B f16x8 gather + 8 v_fma_mix per lane. No barriers (wave-private LDS).
__global__ __launch_bounds__(128) void k_agg(const int* __restrict__ csr_col,
                                             const int* __restrict__ offs,
                                             const int* __restrict__ deg,
                                             const float* __restrict__ al,
                                             const float* __restrict__ ar,
                                             const _Float16* __restrict__ h16,
                                             float* __restrict__ out) {
    __shared__ float s_w[2][64][4];   // [wave][edge][head]
    __shared__ int   s_c[2][64];
    const int t = threadIdx.x;
    const int w = t >> 6;
    const int l = t & 63;
    const int r = blockIdx.x * 2 + w;     // 25000 blocks x 2
    const int eslot = l >> 5;
    const int j = l & 31;
    const int hd = j >> 3;
    const int dg = deg[r];
    const int start = offs[r];

    const float4 alv = *(const float4*)&al[r * NHEAD];
    const float4* __restrict__ ar4 = (const float4*)ar;
    const f16x8* __restrict__ h8 = (const f16x8*)h16;

    float acc[8];
#pragma unroll
    for (int k = 0; k < 8; ++k) acc[k] = 0.f;
    float4 ps = make_float4(0.f, 0.f, 0.f, 0.f);

    for (int c0 = 0; c0 < dg; c0 += 64) {
        const int n = min(64, dg - c0);
        if (l < n) {
            int c = csr_col[start + c0 + l];
            s_c[w][l] = c;
            float4 arv = ar4[c];
            float e0 = alv.x + arv.x; e0 = (e0 >= 0.f) ? e0 : LRELU_ALPHA * e0;
            float e1 = alv.y + arv.y; e1 = (e1 >= 0.f) ? e1 : LRELU_ALPHA * e1;
            float e2 = alv.z + arv.z; e2 = (e2 >= 0.f) ? e2 : LRELU_ALPHA * e2;
            float e3 = alv.w + arv.w; e3 = (e3 >= 0.f) ? e3 : LRELU_ALPHA * e3;
            float4 wv;
            wv.x = __expf(fminf(e0, 80.f));
            wv.y = __expf(fminf(e1, 80.f));
            wv.z = __expf(fminf(e2, 80.f));
            wv.w = __expf(fminf(e3, 80.f));
            *(float4*)&s_w[w][l][0] = wv;
            ps.x += wv.x; ps.y += wv.y; ps.z += wv.z; ps.w += wv.w;
        }
        // wave-internal LDS write->read: lgkmcnt dependency suffices, no barrier.
        const int np = (n + 1) >> 1;
#pragma unroll 4
        for (int p = 0; p < np; ++p) {
            int i0 = 2 * p + eslot;
            bool v = (i0 < n);
            int c = v ? s_c[w][i0] : s_c[w][0];
            float wt = v ? s_w[w][i0][hd] : 0.f;
            f16x8 hv = h8[(unsigned)((c << 5) | j)];   // 16B coalesced gather
#pragma unroll
            for (int k = 0; k < 8; ++k)
                acc[k] += (float)hv[k] * wt;           // v_fma_mix_f32
        }
    }

    // combine the two edge slots
#pragma unroll
    for (int k = 0; k < 8; ++k) acc[k] += __shfl_xor(acc[k], 32);

    // wave-reduce denominator (all heads), select this lane's head
#pragma unroll
    for (int s = 1; s <= 32; s <<= 1) {
        ps.x += __shfl_xor(ps.x, s);
        ps.y += __shfl_xor(ps.y, s);
        ps.z += __shfl_xor(ps.z, s);
        ps.w += __shfl_xor(ps.w, s);
    }
    float den = (hd == 0) ? ps.x : (hd == 1) ? ps.y : (hd == 2) ? ps.z : ps.w;
    float inv = (den > 0.f) ? 1.f / den : 0.f;
    if (l < 32) {
        float4 o0 = make_float4(acc[0] * inv, acc[1] * inv, acc[2] * inv, acc[3] * inv);
        float4 o1 = make_float4(acc[4] * inv, acc[5] * inv, acc[6] * inv, acc[7] * inv);
        float4* op = (float4*)&out[((size_t)r << 8) + j * 8];
        op[0] = o0;
        op[1] = o1;
    }
}

extern "C" void kernel_launch(void* const* d_in, const int* in_sizes, int n_in,
                              void* d_out, int out_size, void* d_ws, size_t ws_size,
                              hipStream_t stream) {
    const float* x   = (const float*)d_in[0];
    const int*   ei  = (const int*)d_in[1];
    const float* Wm  = (const float*)d_in[2];
    const float* a_l = (const float*)d_in[3];
    const float* a_r = (const float*)d_in[4];
    float* out = (float*)d_out;

    _Float16* h16 = (_Float16*)d_ws;                              // N*256 f16
    _Float16* Wh  = h16 + (size_t)N_NODES * OUT_C;                // 64K f16
    float* al  = (float*)(Wh + 256 * 256);                        // N*4
    float* ar  = al + (size_t)N_NODES * NHEAD;                    // N*4
    int* deg    = (int*)(ar + (size_t)N_NODES * NHEAD);           // N
    int* offs   = deg + N_NODES;                                  // N
    int* incl   = offs + N_NODES;                                 // N
    int* bsums  = incl + N_NODES;                                 // 128
    int* rank   = bsums + 128;                                    // E
    int* csr_col = rank + N_EDGES;                                // E

    hipMemsetAsync(deg, 0, N_NODES * sizeof(int), stream);        // deg only

    k_convw<<<256, 256, 0, stream>>>(Wm, Wh);
    k_gemm_hist<<<GEMM_NB + HIST_NB, 256, 0, stream>>>(x, Wh, a_l, a_r, h16, al, ar,
                                                       ei, deg, rank);
    k_scanA<<<SCAN_NB, SCAN_BS, 0, stream>>>(deg, incl, bsums);
    k_scanB<<<SCAN_NB, SCAN_BS, 0, stream>>>(deg, incl, bsums, offs);
    for (int p = 0; p < 4; ++p)
        k_scatter<<<HIST_NB, 256, 0, stream>>>(ei, rank, offs, csr_col, p * 12500);
    k_agg<<<N_NODES / 2, 128, 0, stream>>>(csr_col, offs, deg, al, ar, h16, out);
}

// Round 12
// 252.274 us; speedup vs baseline: 1.0062x; 1.0062x over previous
//
#include <hip/hip_runtime.h>
#include <hip/hip_bf16.h>

#define N_NODES 50000
#define N_EDGES 1600000
#define IN_F 256
#define OUT_C 256   // OUT_F * NHEAD
#define NHEAD 4
#define HEAD_F 64
#define LRELU_ALPHA 0.2f

#define SCAN_BS 512
#define SCAN_NB ((N_NODES + SCAN_BS - 1) / SCAN_BS)   // 98

typedef __attribute__((ext_vector_type(8))) _Float16 f16x8;
typedef __attribute__((ext_vector_type(4))) float f32x4;

// ---------------- W pre-convert: f32 [K][N] -> chunked f16 ----------------
__global__ __launch_bounds__(256) void k_convw(const float* __restrict__ Wm,
                                               _Float16* __restrict__ Wh) {
    int t = blockIdx.x * 256 + threadIdx.x;   // t == k*256+n
    int k = t >> 8, n = t & 255;
    Wh[((k >> 3) * 256 + n) * 8 + (k & 7)] = (_Float16)Wm[t];
}

// ---------------- fused GEMM + ranked histogram (hist appended after gemm) -------
// blocks [0, GEMM_NB): MFMA gemm. blocks [GEMM_NB, +6250): rank[e] =
// atomicAdd(&deg[r],1) — latency-bound, drains while gemm blocks retire.
#define BM 128
#define BK 32
#define GEMM_NB ((N_NODES + BM - 1) / BM)        // 391
#define HIST_NB ((N_EDGES + 255) / 256)          // 6250
__global__ __launch_bounds__(256, 2) void k_gemm_hist(const float* __restrict__ x,
                                                      const _Float16* __restrict__ Wh,
                                                      const float* __restrict__ a_l,
                                                      const float* __restrict__ a_r,
                                                      _Float16* __restrict__ h16,
                                                      float* __restrict__ al_out,
                                                      float* __restrict__ ar_out,
                                                      const int* __restrict__ ei,
                                                      int* __restrict__ deg,
                                                      int* __restrict__ rank) {
    __shared__ _Float16 Ah[4 * 128 * 8];    // [kk][row][8]  8 KB
    __shared__ _Float16 Bh[4 * 256 * 8];    // [kk][col][8] 16 KB
    __shared__ float s_al[256], s_ar[256];

    if (blockIdx.x >= GEMM_NB) {
        int e = (blockIdx.x - GEMM_NB) * 256 + threadIdx.x;
        if (e < N_EDGES) rank[e] = atomicAdd(&deg[ei[e]], 1);
        return;
    }

    const int t = threadIdx.x;
    const int w = t >> 6;
    const int l = t & 63;
    const int row0 = blockIdx.x * BM;

    s_al[t] = a_l[t];
    s_ar[t] = a_r[t];

    f32x4 acc0[16], acc1[16];
#pragma unroll
    for (int c = 0; c < 16; ++c) { acc0[c] = (f32x4)(0.f); acc1[c] = (f32x4)(0.f); }

    const int kk_r = l >> 4;
    const int li   = l & 15;

    for (int ks = 0; ks < 8; ++ks) {
        const int k0 = ks * BK;
        __syncthreads();
        // ---- stage A: 512 chunks (kk 0..3 x row 0..127); thread t does q=t, t+256
#pragma unroll
        for (int s = 0; s < 2; ++s) {
            int q = t + s * 256;
            int kk = q & 3, row = q >> 2;
            int grow = row0 + row;
            float4 v0 = make_float4(0.f, 0.f, 0.f, 0.f);
            float4 v1 = make_float4(0.f, 0.f, 0.f, 0.f);
            if (grow < N_NODES) {
                const float* src = &x[(size_t)grow * IN_F + k0 + kk * 8];
                v0 = *(const float4*)src;
                v1 = *(const float4*)(src + 4);
            }
            float f[8] = {v0.x, v0.y, v0.z, v0.w, v1.x, v1.y, v1.z, v1.w};
            f16x8 vh;
#pragma unroll
            for (int jj = 0; jj < 8; ++jj) vh[jj] = (_Float16)f[jj];
            *(f16x8*)&Ah[(kk * 128 + row) * 8] = vh;
        }
        // ---- stage B: 1024 chunks; thread t does q = t + s*256, s<4
        {
            const size_t tb = (size_t)(k0 >> 3) * 256 * 8;
#pragma unroll
            for (int s = 0; s < 4; ++s) {
                int q = s * 256 + t;
                *(f16x8*)&Bh[q * 8] = *(const f16x8*)&Wh[tb + (size_t)q * 8];
            }
        }
        __syncthreads();
        f16x8 a0 = *(f16x8*)&Ah[(kk_r * 128 + w * 16 + li) * 8];
        f16x8 a1 = *(f16x8*)&Ah[(kk_r * 128 + (w + 4) * 16 + li) * 8];
#pragma unroll
        for (int c = 0; c < 16; ++c) {
            f16x8 bh = *(f16x8*)&Bh[(kk_r * 256 + c * 16 + li) * 8];
            acc0[c] = __builtin_amdgcn_mfma_f32_16x16x32_f16(a0, bh, acc0[c], 0, 0, 0);
            acc1[c] = __builtin_amdgcn_mfma_f32_16x16x32_f16(a1, bh, acc1[c], 0, 0, 0);
        }
    }

    // ---- epilogue per row-tile: C layout row=(l>>4)*4+j, col=c*16+li ----
#pragma unroll
    for (int rt = 0; rt < 2; ++rt) {
        const int rbase = row0 + (w + rt * 4) * 16 + ((l >> 4) << 2);
#pragma unroll
        for (int c = 0; c < 16; ++c) {
#pragma unroll
            for (int j = 0; j < 4; ++j) {
                int row = rbase + j;
                float v = rt ? acc1[c][j] : acc0[c][j];
                if (row < N_NODES)
                    h16[(size_t)row * OUT_C + c * 16 + li] = (_Float16)v;
            }
        }
        // fused al/ar: column c*16+li belongs to head c>>2 (compile-time per c).
        float plh[4][4], prh[4][4];   // [head][j]
#pragma unroll
        for (int hd = 0; hd < 4; ++hd)
#pragma unroll
            for (int j = 0; j < 4; ++j) { plh[hd][j] = 0.f; prh[hd][j] = 0.f; }
#pragma unroll
        for (int c = 0; c < 16; ++c) {
            float av = s_al[c * 16 + li];
            float bv = s_ar[c * 16 + li];
#pragma unroll
            for (int j = 0; j < 4; ++j) {
                float v = rt ? acc1[c][j] : acc0[c][j];
                plh[c >> 2][j] += av * v;
                prh[c >> 2][j] += bv * v;
            }
        }
#pragma unroll
        for (int hd = 0; hd < 4; ++hd)
#pragma unroll
            for (int j = 0; j < 4; ++j)
#pragma unroll
                for (int s = 1; s <= 8; s <<= 1) {
                    plh[hd][j] += __shfl_xor(plh[hd][j], s);
                    prh[hd][j] += __shfl_xor(prh[hd][j], s);
                }
        if (li == 0) {
#pragma unroll
            for (int j = 0; j < 4; ++j) {
                int row = rbase + j;
                if (row < N_NODES) {
#pragma unroll
                    for (int hd = 0; hd < 4; ++hd) {
                        al_out[row * NHEAD + hd] = plh[hd][j];
                        ar_out[row * NHEAD + hd] = prh[hd][j];
                    }
                }
            }
        }
    }
}

// ---------------- fused scan (ticket): per-block inclusive scan; last block
// scans the 98 block sums and writes offs[] for all nodes (coalesced).
__global__ __launch_bounds__(SCAN_BS) void k_scanAB(const int* __restrict__ deg,
                                                    int* __restrict__ incl,
                                                    int* __restrict__ bsums,
                                                    int* __restrict__ ticket,
                                                    int* __restrict__ offs) {
    __shared__ int sm[SCAN_BS];
    __shared__ int sb[128];
    __shared__ int bo[128];
    __shared__ int s_last;
    const int tid = threadIdx.x;
    const int i = blockIdx.x * SCAN_BS + tid;
    int v = (i < N_NODES) ? deg[i] : 0;
    sm[tid] = v;
    __syncthreads();
    for (int off = 1; off < SCAN_BS; off <<= 1) {
        int add = (tid >= off) ? sm[tid - off] : 0;
        __syncthreads();
        sm[tid] += add;
        __syncthreads();
    }
    if (i < N_NODES) incl[i] = sm[tid];
    if (tid == SCAN_BS - 1) bsums[blockIdx.x] = sm[tid];
    __threadfence();
    if (tid == 0) s_last = (atomicAdd(ticket, 1) == SCAN_NB - 1);
    __syncthreads();
    if (s_last) {
        __threadfence();   // acquire all writers' incl/bsums
        int b = 0;
        if (tid < 128) { b = (tid < SCAN_NB) ? bsums[tid] : 0; sb[tid] = b; }
        __syncthreads();
        for (int off = 1; off < 128; off <<= 1) {
            int add = (tid >= off && tid < 128) ? sb[tid - off] : 0;
            __syncthreads();
            if (tid < 128) sb[tid] += add;
            __syncthreads();
        }
        if (tid < 128) bo[tid] = sb[tid] - b;   // exclusive block offset
        __syncthreads();
        for (int n = tid; n < N_NODES; n += SCAN_BS)
            offs[n] = incl[n] - deg[n] + bo[n >> 9];   // 512 = 1<<9
    }
}

// ---------------- CSR scatter: atomic-free (pos = offs[r] + rank[e]) -------------
__global__ __launch_bounds__(256) void k_scatter(const int* __restrict__ ei,
                                                 const int* __restrict__ rank,
                                                 const int* __restrict__ offs,
                                                 int* __restrict__ csr_col) {
    int e = blockIdx.x * 256 + threadIdx.x;
    if (e < N_EDGES) {
        int r = ei[e];
        csr_col[offs[r] + rank[e]] = ei[N_EDGES + e];
    }
}

// ---------------- per-row segment softmax + SpMM: ONE WAVE PER ROW ----------------
// 128 threads = 2 waves = 2 rows. Lane l: edge slot l>>5, feature block j=l&31
// (features 8j..8j+7, head j>>3). Per iter a wave consumes 2 edges:
// one 16B f16x8 gather + 8 v_fma_mix per lane. No barriers (wave-private LDS).
__global__ __launch_bounds__(128) void k_agg(const int* __restrict__ csr_col,
                                             const int* __restrict__ offs,
                                             const int* __restrict__ deg,
                                             const float* __restrict__ al,
                                             const float* __restrict__ ar,
                                             const _Float16* __restrict__ h16,
                                             float* __restrict__ out) {
    __shared__ float s_w[2][64][4];   // [wave][edge][head]
    __shared__ int   s_c[2][64];
    const int t = threadIdx.x;
    const int w = t >> 6;
    const int l = t & 63;
    const int r = blockIdx.x * 2 + w;     // 25000 blocks x 2
    const int eslot = l >> 5;
    const int j = l & 31;
    const int hd = j >> 3;
    const int dg = deg[r];
    const int start = offs[r];

    const float4 alv = *(const float4*)&al[r * NHEAD];
    const float4* __restrict__ ar4 = (const float4*)ar;
    const f16x8* __restrict__ h8 = (const f16x8*)h16;

    float acc[8];
#pragma unroll
    for (int k = 0; k < 8; ++k) acc[k] = 0.f;
    float4 ps = make_float4(0.f, 0.f, 0.f, 0.f);

    for (int c0 = 0; c0 < dg; c0 += 64) {
        const int n = min(64, dg - c0);
        if (l < n) {
            int c = csr_col[start + c0 + l];
            s_c[w][l] = c;
            float4 arv = ar4[c];
            float e0 = alv.x + arv.x; e0 = (e0 >= 0.f) ? e0 : LRELU_ALPHA * e0;
            float e1 = alv.y + arv.y; e1 = (e1 >= 0.f) ? e1 : LRELU_ALPHA * e1;
            float e2 = alv.z + arv.z; e2 = (e2 >= 0.f) ? e2 : LRELU_ALPHA * e2;
            float e3 = alv.w + arv.w; e3 = (e3 >= 0.f) ? e3 : LRELU_ALPHA * e3;
            float4 wv;
            wv.x = __expf(fminf(e0, 80.f));
            wv.y = __expf(fminf(e1, 80.f));
            wv.z = __expf(fminf(e2, 80.f));
            wv.w = __expf(fminf(e3, 80.f));
            *(float4*)&s_w[w][l][0] = wv;
            ps.x += wv.x; ps.y += wv.y; ps.z += wv.z; ps.w += wv.w;
        }
        // wave-internal LDS write->read: lgkmcnt dependency suffices, no barrier.
        const int np = (n + 1) >> 1;
#pragma unroll 4
        for (int p = 0; p < np; ++p) {
            int i0 = 2 * p + eslot;
            bool v = (i0 < n);
            int c = v ? s_c[w][i0] : s_c[w][0];
            float wt = v ? s_w[w][i0][hd] : 0.f;
            f16x8 hv = h8[(unsigned)((c << 5) | j)];   // 16B coalesced gather
#pragma unroll
            for (int k = 0; k < 8; ++k)
                acc[k] += (float)hv[k] * wt;           // v_fma_mix_f32
        }
    }

    // combine the two edge slots
#pragma unroll
    for (int k = 0; k < 8; ++k) acc[k] += __shfl_xor(acc[k], 32);

    // wave-reduce denominator (all heads), select this lane's head
#pragma unroll
    for (int s = 1; s <= 32; s <<= 1) {
        ps.x += __shfl_xor(ps.x, s);
        ps.y += __shfl_xor(ps.y, s);
        ps.z += __shfl_xor(ps.z, s);
        ps.w += __shfl_xor(ps.w, s);
    }
    float den = (hd == 0) ? ps.x : (hd == 1) ? ps.y : (hd == 2) ? ps.z : ps.w;
    float inv = (den > 0.f) ? 1.f / den : 0.f;
    if (l < 32) {
        float4 o0 = make_float4(acc[0] * inv, acc[1] * inv, acc[2] * inv, acc[3] * inv);
        float4 o1 = make_float4(acc[4] * inv, acc[5] * inv, acc[6] * inv, acc[7] * inv);
        float4* op = (float4*)&out[((size_t)r << 8) + j * 8];
        op[0] = o0;
        op[1] = o1;
    }
}

extern "C" void kernel_launch(void* const* d_in, const int* in_sizes, int n_in,
                              void* d_out, int out_size, void* d_ws, size_t ws_size,
                              hipStream_t stream) {
    const float* x   = (const float*)d_in[0];
    const int*   ei  = (const int*)d_in[1];
    const float* Wm  = (const float*)d_in[2];
    const float* a_l = (const float*)d_in[3];
    const float* a_r = (const float*)d_in[4];
    float* out = (float*)d_out;

    _Float16* h16 = (_Float16*)d_ws;                              // N*256 f16
    _Float16* Wh  = h16 + (size_t)N_NODES * OUT_C;                // 64K f16
    float* al  = (float*)(Wh + 256 * 256);                        // N*4
    float* ar  = al + (size_t)N_NODES * NHEAD;                    // N*4
    int* deg    = (int*)(ar + (size_t)N_NODES * NHEAD);           // N
    int* ticket = deg + N_NODES;                                  // 1
    int* offs   = ticket + 1;                                     // N
    int* incl   = offs + N_NODES;                                 // N
    int* bsums  = incl + N_NODES;                                 // 128
    int* rank   = bsums + 128;                                    // E
    int* csr_col = rank + N_EDGES;                                // E

    hipMemsetAsync(deg, 0, (N_NODES + 1) * sizeof(int), stream);  // deg + ticket

    k_convw<<<256, 256, 0, stream>>>(Wm, Wh);
    k_gemm_hist<<<GEMM_NB + HIST_NB, 256, 0, stream>>>(x, Wh, a_l, a_r, h16, al, ar,
                                                       ei, deg, rank);
    k_scanAB<<<SCAN_NB, SCAN_BS, 0, stream>>>(deg, incl, bsums, ticket, offs);
    k_scatter<<<HIST_NB, 256, 0, stream>>>(ei, rank, offs, csr_col);
    k_agg<<<N_NODES / 2, 128, 0, stream>>>(csr_col, offs, deg, al, ar, h16, out);
}

// Round 13
// 229.170 us; speedup vs baseline: 1.1076x; 1.1008x over previous
//
#include <hip/hip_runtime.h>
#include <hip/hip_bf16.h>

#define N_NODES 50000
#define N_EDGES 1600000
#define IN_F 256
#define OUT_C 256   // OUT_F * NHEAD
#define NHEAD 4
#define HEAD_F 64
#define LRELU_ALPHA 0.2f

#define SCAN_BS 512
#define SCAN_NB ((N_NODES + SCAN_BS - 1) / SCAN_BS)   // 98

typedef __attribute__((ext_vector_type(8))) _Float16 f16x8;
typedef __attribute__((ext_vector_type(4))) float f32x4;

// ---------------- W pre-convert: f32 [K][N] -> chunked f16 ----------------
__global__ __launch_bounds__(256) void k_convw(const float* __restrict__ Wm,
                                               _Float16* __restrict__ Wh) {
    int t = blockIdx.x * 256 + threadIdx.x;   // t == k*256+n
    int k = t >> 8, n = t & 255;
    Wh[((k >> 3) * 256 + n) * 8 + (k & 7)] = (_Float16)Wm[t];
}

// ---------------- fused GEMM + ranked histogram (hist appended after gemm) -------
// blocks [0, GEMM_NB): MFMA gemm. blocks [GEMM_NB, +6250): rank[e] =
// atomicAdd(&deg[r],1) — latency-bound, drains while gemm blocks retire.
#define BM 128
#define BK 32
#define GEMM_NB ((N_NODES + BM - 1) / BM)        // 391
#define HIST_NB ((N_EDGES + 255) / 256)          // 6250
__global__ __launch_bounds__(256, 2) void k_gemm_hist(const float* __restrict__ x,
                                                      const _Float16* __restrict__ Wh,
                                                      const float* __restrict__ a_l,
                                                      const float* __restrict__ a_r,
                                                      _Float16* __restrict__ h16,
                                                      float* __restrict__ al_out,
                                                      float* __restrict__ ar_out,
                                                      const int* __restrict__ ei,
                                                      int* __restrict__ deg,
                                                      int* __restrict__ rank) {
    __shared__ _Float16 Ah[4 * 128 * 8];    // [kk][row][8]  8 KB
    __shared__ _Float16 Bh[4 * 256 * 8];    // [kk][col][8] 16 KB
    __shared__ float s_al[256], s_ar[256];

    if (blockIdx.x >= GEMM_NB) {
        int e = (blockIdx.x - GEMM_NB) * 256 + threadIdx.x;
        if (e < N_EDGES) rank[e] = atomicAdd(&deg[ei[e]], 1);
        return;
    }

    const int t = threadIdx.x;
    const int w = t >> 6;
    const int l = t & 63;
    const int row0 = blockIdx.x * BM;

    s_al[t] = a_l[t];
    s_ar[t] = a_r[t];

    f32x4 acc0[16], acc1[16];
#pragma unroll
    for (int c = 0; c < 16; ++c) { acc0[c] = (f32x4)(0.f); acc1[c] = (f32x4)(0.f); }

    const int kk_r = l >> 4;
    const int li   = l & 15;

    for (int ks = 0; ks < 8; ++ks) {
        const int k0 = ks * BK;
        __syncthreads();
        // ---- stage A: 512 chunks (kk 0..3 x row 0..127); thread t does q=t, t+256
#pragma unroll
        for (int s = 0; s < 2; ++s) {
            int q = t + s * 256;
            int kk = q & 3, row = q >> 2;
            int grow = row0 + row;
            float4 v0 = make_float4(0.f, 0.f, 0.f, 0.f);
            float4 v1 = make_float4(0.f, 0.f, 0.f, 0.f);
            if (grow < N_NODES) {
                const float* src = &x[(size_t)grow * IN_F + k0 + kk * 8];
                v0 = *(const float4*)src;
                v1 = *(const float4*)(src + 4);
            }
            float f[8] = {v0.x, v0.y, v0.z, v0.w, v1.x, v1.y, v1.z, v1.w};
            f16x8 vh;
#pragma unroll
            for (int jj = 0; jj < 8; ++jj) vh[jj] = (_Float16)f[jj];
            *(f16x8*)&Ah[(kk * 128 + row) * 8] = vh;
        }
        // ---- stage B: 1024 chunks; thread t does q = t + s*256, s<4
        {
            const size_t tb = (size_t)(k0 >> 3) * 256 * 8;
#pragma unroll
            for (int s = 0; s < 4; ++s) {
                int q = s * 256 + t;
                *(f16x8*)&Bh[q * 8] = *(const f16x8*)&Wh[tb + (size_t)q * 8];
            }
        }
        __syncthreads();
        f16x8 a0 = *(f16x8*)&Ah[(kk_r * 128 + w * 16 + li) * 8];
        f16x8 a1 = *(f16x8*)&Ah[(kk_r * 128 + (w + 4) * 16 + li) * 8];
#pragma unroll
        for (int c = 0; c < 16; ++c) {
            f16x8 bh = *(f16x8*)&Bh[(kk_r * 256 + c * 16 + li) * 8];
            acc0[c] = __builtin_amdgcn_mfma_f32_16x16x32_f16(a0, bh, acc0[c], 0, 0, 0);
            acc1[c] = __builtin_amdgcn_mfma_f32_16x16x32_f16(a1, bh, acc1[c], 0, 0, 0);
        }
    }

    // ---- epilogue per row-tile: C layout row=(l>>4)*4+j, col=c*16+li ----
#pragma unroll
    for (int rt = 0; rt < 2; ++rt) {
        const int rbase = row0 + (w + rt * 4) * 16 + ((l >> 4) << 2);
#pragma unroll
        for (int c = 0; c < 16; ++c) {
#pragma unroll
            for (int j = 0; j < 4; ++j) {
                int row = rbase + j;
                float v = rt ? acc1[c][j] : acc0[c][j];
                if (row < N_NODES)
                    h16[(size_t)row * OUT_C + c * 16 + li] = (_Float16)v;
            }
        }
        // fused al/ar: column c*16+li belongs to head c>>2 (compile-time per c).
        float plh[4][4], prh[4][4];   // [head][j]
#pragma unroll
        for (int hd = 0; hd < 4; ++hd)
#pragma unroll
            for (int j = 0; j < 4; ++j) { plh[hd][j] = 0.f; prh[hd][j] = 0.f; }
#pragma unroll
        for (int c = 0; c < 16; ++c) {
            float av = s_al[c * 16 + li];
            float bv = s_ar[c * 16 + li];
#pragma unroll
            for (int j = 0; j < 4; ++j) {
                float v = rt ? acc1[c][j] : acc0[c][j];
                plh[c >> 2][j] += av * v;
                prh[c >> 2][j] += bv * v;
            }
        }
#pragma unroll
        for (int hd = 0; hd < 4; ++hd)
#pragma unroll
            for (int j = 0; j < 4; ++j)
#pragma unroll
                for (int s = 1; s <= 8; s <<= 1) {
                    plh[hd][j] += __shfl_xor(plh[hd][j], s);
                    prh[hd][j] += __shfl_xor(prh[hd][j], s);
                }
        if (li == 0) {
#pragma unroll
            for (int j = 0; j < 4; ++j) {
                int row = rbase + j;
                if (row < N_NODES) {
#pragma unroll
                    for (int hd = 0; hd < 4; ++hd) {
                        al_out[row * NHEAD + hd] = plh[hd][j];
                        ar_out[row * NHEAD + hd] = prh[hd][j];
                    }
                }
            }
        }
    }
}

// ---------------- scanA: per-block inclusive scan of deg ----------------
__global__ __launch_bounds__(SCAN_BS) void k_scanA(const int* __restrict__ deg,
                                                   int* __restrict__ incl,
                                                   int* __restrict__ bsums) {
    __shared__ int sm[SCAN_BS];
    const int tid = threadIdx.x;
    const int i = blockIdx.x * SCAN_BS + tid;
    int v = (i < N_NODES) ? deg[i] : 0;
    sm[tid] = v;
    __syncthreads();
    for (int off = 1; off < SCAN_BS; off <<= 1) {
        int add = (tid >= off) ? sm[tid - off] : 0;
        __syncthreads();
        sm[tid] += add;
        __syncthreads();
    }
    if (i < N_NODES) incl[i] = sm[tid];
    if (tid == SCAN_BS - 1) bsums[blockIdx.x] = sm[tid];
}

// ---------------- scanB: each block redundantly scans bsums, writes offs chunk ----
__global__ __launch_bounds__(SCAN_BS) void k_scanB(const int* __restrict__ deg,
                                                   const int* __restrict__ incl,
                                                   const int* __restrict__ bsums,
                                                   int* __restrict__ offs) {
    __shared__ int sb[128];
    const int tid = threadIdx.x;
    const int bid = blockIdx.x;
    if (tid < 128) sb[tid] = (tid < SCAN_NB) ? bsums[tid] : 0;
    __syncthreads();
    for (int off = 1; off < 128; off <<= 1) {
        int add = (tid >= off && tid < 128) ? sb[tid - off] : 0;
        __syncthreads();
        if (tid < 128) sb[tid] += add;
        __syncthreads();
    }
    const int bo = (bid == 0) ? 0 : sb[bid - 1];   // exclusive block offset
    const int n = bid * SCAN_BS + tid;
    if (n < N_NODES) offs[n] = incl[n] - deg[n] + bo;
}

// ---------------- CSR scatter: atomic-free, ushort payload ----------------
// col index < 50000 < 65536 -> store as ushort: halves the random-write
// footprint (64B line holds 32 entries) and k_agg's csr read bytes.
__global__ __launch_bounds__(256) void k_scatter(const int* __restrict__ ei,
                                                 const int* __restrict__ rank,
                                                 const int* __restrict__ offs,
                                                 unsigned short* __restrict__ csr_col) {
    int e = blockIdx.x * 256 + threadIdx.x;
    if (e < N_EDGES) {
        int r = ei[e];
        csr_col[offs[r] + rank[e]] = (unsigned short)ei[N_EDGES + e];
    }
}

// ---------------- per-row segment softmax + SpMM: ONE WAVE PER ROW ----------------
// 128 threads = 2 waves = 2 rows. Lane l: edge slot l>>5, feature block j=l&31
// (features 8j..8j+7, head j>>3). Per iter a wave consumes 2 edges:
// one 16B f16x8 gather + 8 v_fma_mix per lane. No barriers (wave-private LDS).
__global__ __launch_bounds__(128) void k_agg(const unsigned short* __restrict__ csr_col,
                                             const int* __restrict__ offs,
                                             const int* __restrict__ deg,
                                             const float* __restrict__ al,
                                             const float* __restrict__ ar,
                                             const _Float16* __restrict__ h16,
                                             float* __restrict__ out) {
    __shared__ float s_w[2][64][4];   // [wave][edge][head]
    __shared__ int   s_c[2][64];
    const int t = threadIdx.x;
    const int w = t >> 6;
    const int l = t & 63;
    const int r = blockIdx.x * 2 + w;     // 25000 blocks x 2
    const int eslot = l >> 5;
    const int j = l & 31;
    const int hd = j >> 3;
    const int dg = deg[r];
    const int start = offs[r];

    const float4 alv = *(const float4*)&al[r * NHEAD];
    const float4* __restrict__ ar4 = (const float4*)ar;
    const f16x8* __restrict__ h8 = (const f16x8*)h16;

    float acc[8];
#pragma unroll
    for (int k = 0; k < 8; ++k) acc[k] = 0.f;
    float4 ps = make_float4(0.f, 0.f, 0.f, 0.f);

    for (int c0 = 0; c0 < dg; c0 += 64) {
        const int n = min(64, dg - c0);
        if (l < n) {
            int c = csr_col[start + c0 + l];
            s_c[w][l] = c;
            float4 arv = ar4[c];
            float e0 = alv.x + arv.x; e0 = (e0 >= 0.f) ? e0 : LRELU_ALPHA * e0;
            float e1 = alv.y + arv.y; e1 = (e1 >= 0.f) ? e1 : LRELU_ALPHA * e1;
            float e2 = alv.z + arv.z; e2 = (e2 >= 0.f) ? e2 : LRELU_ALPHA * e2;
            float e3 = alv.w + arv.w; e3 = (e3 >= 0.f) ? e3 : LRELU_ALPHA * e3;
            float4 wv;
            wv.x = __expf(fminf(e0, 80.f));
            wv.y = __expf(fminf(e1, 80.f));
            wv.z = __expf(fminf(e2, 80.f));
            wv.w = __expf(fminf(e3, 80.f));
            *(float4*)&s_w[w][l][0] = wv;
            ps.x += wv.x; ps.y += wv.y; ps.z += wv.z; ps.w += wv.w;
        }
        // wave-internal LDS write->read: lgkmcnt dependency suffices, no barrier.
        const int np = (n + 1) >> 1;
#pragma unroll 4
        for (int p = 0; p < np; ++p) {
            int i0 = 2 * p + eslot;
            bool v = (i0 < n);
            int c = v ? s_c[w][i0] : s_c[w][0];
            float wt = v ? s_w[w][i0][hd] : 0.f;
            f16x8 hv = h8[(unsigned)((c << 5) | j)];   // 16B coalesced gather
#pragma unroll
            for (int k = 0; k < 8; ++k)
                acc[k] += (float)hv[k] * wt;           // v_fma_mix_f32
        }
    }

    // combine the two edge slots
#pragma unroll
    for (int k = 0; k < 8; ++k) acc[k] += __shfl_xor(acc[k], 32);

    // wave-reduce denominator (all heads), select this lane's head
#pragma unroll
    for (int s = 1; s <= 32; s <<= 1) {
        ps.x += __shfl_xor(ps.x, s);
        ps.y += __shfl_xor(ps.y, s);
        ps.z += __shfl_xor(ps.z, s);
        ps.w += __shfl_xor(ps.w, s);
    }
    float den = (hd == 0) ? ps.x : (hd == 1) ? ps.y : (hd == 2) ? ps.z : ps.w;
    float inv = (den > 0.f) ? 1.f / den : 0.f;
    if (l < 32) {
        float4 o0 = make_float4(acc[0] * inv, acc[1] * inv, acc[2] * inv, acc[3] * inv);
        float4 o1 = make_float4(acc[4] * inv, acc[5] * inv, acc[6] * inv, acc[7] * inv);
        float4* op = (float4*)&out[((size_t)r << 8) + j * 8];
        op[0] = o0;
        op[1] = o1;
    }
}

extern "C" void kernel_launch(void* const* d_in, const int* in_sizes, int n_in,
                              void* d_out, int out_size, void* d_ws, size_t ws_size,
                              hipStream_t stream) {
    const float* x   = (const float*)d_in[0];
    const int*   ei  = (const int*)d_in[1];
    const float* Wm  = (const float*)d_in[2];
    const float* a_l = (const float*)d_in[3];
    const float* a_r = (const float*)d_in[4];
    float* out = (float*)d_out;

    _Float16* h16 = (_Float16*)d_ws;                              // N*256 f16
    _Float16* Wh  = h16 + (size_t)N_NODES * OUT_C;                // 64K f16
    float* al  = (float*)(Wh + 256 * 256);                        // N*4
    float* ar  = al + (size_t)N_NODES * NHEAD;                    // N*4
    int* deg    = (int*)(ar + (size_t)N_NODES * NHEAD);           // N
    int* offs   = deg + N_NODES;                                  // N
    int* incl   = offs + N_NODES;                                 // N
    int* bsums  = incl + N_NODES;                                 // 128
    int* rank   = bsums + 128;                                    // E
    unsigned short* csr_col = (unsigned short*)(rank + N_EDGES);  // E ushort

    hipMemsetAsync(deg, 0, N_NODES * sizeof(int), stream);        // deg only

    k_convw<<<256, 256, 0, stream>>>(Wm, Wh);
    k_gemm_hist<<<GEMM_NB + HIST_NB, 256, 0, stream>>>(x, Wh, a_l, a_r, h16, al, ar,
                                                       ei, deg, rank);
    k_scanA<<<SCAN_NB, SCAN_BS, 0, stream>>>(deg, incl, bsums);
    k_scanB<<<SCAN_NB, SCAN_BS, 0, stream>>>(deg, incl, bsums, offs);
    k_scatter<<<HIST_NB, 256, 0, stream>>>(ei, rank, offs, csr_col);
    k_agg<<<N_NODES / 2, 128, 0, stream>>>(csr_col, offs, deg, al, ar, h16, out);
}

// Round 14
// 227.514 us; speedup vs baseline: 1.1157x; 1.0073x over previous
//
#include <hip/hip_runtime.h>
#include <hip/hip_bf16.h>

#define N_NODES 50000
#define N_EDGES 1600000
#define IN_F 256
#define OUT_C 256   // OUT_F * NHEAD
#define NHEAD 4
#define HEAD_F 64
#define LRELU_ALPHA 0.2f

#define SCAN_BS 512
#define SCAN_NB ((N_NODES + SCAN_BS - 1) / SCAN_BS)   // 98

typedef __attribute__((ext_vector_type(8))) _Float16 f16x8;
typedef __attribute__((ext_vector_type(4))) float f32x4;

// ---------------- W pre-convert: f32 [K][N] -> chunked f16 ----------------
__global__ __launch_bounds__(256) void k_convw(const float* __restrict__ Wm,
                                               _Float16* __restrict__ Wh) {
    int t = blockIdx.x * 256 + threadIdx.x;   // t == k*256+n
    int k = t >> 8, n = t & 255;
    Wh[((k >> 3) * 256 + n) * 8 + (k & 7)] = (_Float16)Wm[t];
}

// ---------------- fused GEMM + ranked histogram (4-way replicated counters) ------
// blocks [0, GEMM_NB): MFMA gemm. blocks [GEMM_NB, +6250): edge e atomics into
// deg_rep[e&3][r] -> 4x shorter same-address serialization chains; local rank
// stored as ushort.
#define BM 128
#define BK 32
#define GEMM_NB ((N_NODES + BM - 1) / BM)        // 391
#define HIST_NB ((N_EDGES + 255) / 256)          // 6250
__global__ __launch_bounds__(256, 2) void k_gemm_hist(const float* __restrict__ x,
                                                      const _Float16* __restrict__ Wh,
                                                      const float* __restrict__ a_l,
                                                      const float* __restrict__ a_r,
                                                      _Float16* __restrict__ h16,
                                                      float* __restrict__ al_out,
                                                      float* __restrict__ ar_out,
                                                      const int* __restrict__ ei,
                                                      int* __restrict__ deg_rep,
                                                      unsigned short* __restrict__ rank) {
    __shared__ _Float16 Ah[4 * 128 * 8];    // [kk][row][8]  8 KB
    __shared__ _Float16 Bh[4 * 256 * 8];    // [kk][col][8] 16 KB
    __shared__ float s_al[256], s_ar[256];

    if (blockIdx.x >= GEMM_NB) {
        int e = (blockIdx.x - GEMM_NB) * 256 + threadIdx.x;
        if (e < N_EDGES) {
            int r = ei[e];
            int rl = atomicAdd(&deg_rep[(e & 3) * N_NODES + r], 1);
            rank[e] = (unsigned short)rl;
        }
        return;
    }

    const int t = threadIdx.x;
    const int w = t >> 6;
    const int l = t & 63;
    const int row0 = blockIdx.x * BM;

    s_al[t] = a_l[t];
    s_ar[t] = a_r[t];

    f32x4 acc0[16], acc1[16];
#pragma unroll
    for (int c = 0; c < 16; ++c) { acc0[c] = (f32x4)(0.f); acc1[c] = (f32x4)(0.f); }

    const int kk_r = l >> 4;
    const int li   = l & 15;

    for (int ks = 0; ks < 8; ++ks) {
        const int k0 = ks * BK;
        __syncthreads();
        // ---- stage A: 512 chunks (kk 0..3 x row 0..127); thread t does q=t, t+256
#pragma unroll
        for (int s = 0; s < 2; ++s) {
            int q = t + s * 256;
            int kk = q & 3, row = q >> 2;
            int grow = row0 + row;
            float4 v0 = make_float4(0.f, 0.f, 0.f, 0.f);
            float4 v1 = make_float4(0.f, 0.f, 0.f, 0.f);
            if (grow < N_NODES) {
                const float* src = &x[(size_t)grow * IN_F + k0 + kk * 8];
                v0 = *(const float4*)src;
                v1 = *(const float4*)(src + 4);
            }
            float f[8] = {v0.x, v0.y, v0.z, v0.w, v1.x, v1.y, v1.z, v1.w};
            f16x8 vh;
#pragma unroll
            for (int jj = 0; jj < 8; ++jj) vh[jj] = (_Float16)f[jj];
            *(f16x8*)&Ah[(kk * 128 + row) * 8] = vh;
        }
        // ---- stage B: 1024 chunks; thread t does q = t + s*256, s<4
        {
            const size_t tb = (size_t)(k0 >> 3) * 256 * 8;
#pragma unroll
            for (int s = 0; s < 4; ++s) {
                int q = s * 256 + t;
                *(f16x8*)&Bh[q * 8] = *(const f16x8*)&Wh[tb + (size_t)q * 8];
            }
        }
        __syncthreads();
        f16x8 a0 = *(f16x8*)&Ah[(kk_r * 128 + w * 16 + li) * 8];
        f16x8 a1 = *(f16x8*)&Ah[(kk_r * 128 + (w + 4) * 16 + li) * 8];
#pragma unroll
        for (int c = 0; c < 16; ++c) {
            f16x8 bh = *(f16x8*)&Bh[(kk_r * 256 + c * 16 + li) * 8];
            acc0[c] = __builtin_amdgcn_mfma_f32_16x16x32_f16(a0, bh, acc0[c], 0, 0, 0);
            acc1[c] = __builtin_amdgcn_mfma_f32_16x16x32_f16(a1, bh, acc1[c], 0, 0, 0);
        }
    }

    // ---- epilogue per row-tile: C layout row=(l>>4)*4+j, col=c*16+li ----
#pragma unroll
    for (int rt = 0; rt < 2; ++rt) {
        const int rbase = row0 + (w + rt * 4) * 16 + ((l >> 4) << 2);
#pragma unroll
        for (int c = 0; c < 16; ++c) {
#pragma unroll
            for (int j = 0; j < 4; ++j) {
                int row = rbase + j;
                float v = rt ? acc1[c][j] : acc0[c][j];
                if (row < N_NODES)
                    h16[(size_t)row * OUT_C + c * 16 + li] = (_Float16)v;
            }
        }
        // fused al/ar: column c*16+li belongs to head c>>2 (compile-time per c).
        float plh[4][4], prh[4][4];   // [head][j]
#pragma unroll
        for (int hd = 0; hd < 4; ++hd)
#pragma unroll
            for (int j = 0; j < 4; ++j) { plh[hd][j] = 0.f; prh[hd][j] = 0.f; }
#pragma unroll
        for (int c = 0; c < 16; ++c) {
            float av = s_al[c * 16 + li];
            float bv = s_ar[c * 16 + li];
#pragma unroll
            for (int j = 0; j < 4; ++j) {
                float v = rt ? acc1[c][j] : acc0[c][j];
                plh[c >> 2][j] += av * v;
                prh[c >> 2][j] += bv * v;
            }
        }
#pragma unroll
        for (int hd = 0; hd < 4; ++hd)
#pragma unroll
            for (int j = 0; j < 4; ++j)
#pragma unroll
                for (int s = 1; s <= 8; s <<= 1) {
                    plh[hd][j] += __shfl_xor(plh[hd][j], s);
                    prh[hd][j] += __shfl_xor(prh[hd][j], s);
                }
        if (li == 0) {
#pragma unroll
            for (int j = 0; j < 4; ++j) {
                int row = rbase + j;
                if (row < N_NODES) {
#pragma unroll
                    for (int hd = 0; hd < 4; ++hd) {
                        al_out[row * NHEAD + hd] = plh[hd][j];
                        ar_out[row * NHEAD + hd] = prh[hd][j];
                    }
                }
            }
        }
    }
}

// ---------------- scanA: sum replicas -> degsum; per-block inclusive scan --------
__global__ __launch_bounds__(SCAN_BS) void k_scanA(const int* __restrict__ deg_rep,
                                                   int* __restrict__ degsum,
                                                   int* __restrict__ incl,
                                                   int* __restrict__ bsums) {
    __shared__ int sm[SCAN_BS];
    const int tid = threadIdx.x;
    const int i = blockIdx.x * SCAN_BS + tid;
    int v = 0;
    if (i < N_NODES) {
        v = deg_rep[i] + deg_rep[N_NODES + i] + deg_rep[2 * N_NODES + i]
          + deg_rep[3 * N_NODES + i];
        degsum[i] = v;
    }
    sm[tid] = v;
    __syncthreads();
    for (int off = 1; off < SCAN_BS; off <<= 1) {
        int add = (tid >= off) ? sm[tid - off] : 0;
        __syncthreads();
        sm[tid] += add;
        __syncthreads();
    }
    if (i < N_NODES) incl[i] = sm[tid];
    if (tid == SCAN_BS - 1) bsums[blockIdx.x] = sm[tid];
}

// ---------------- scanB: redundant bsums scan; writes repoff[4][N] ---------------
// repoff[j][n] = row start + prefix of replicas 0..j-1; repoff[0] == offs.
__global__ __launch_bounds__(SCAN_BS) void k_scanB(const int* __restrict__ deg_rep,
                                                   const int* __restrict__ degsum,
                                                   const int* __restrict__ incl,
                                                   const int* __restrict__ bsums,
                                                   int* __restrict__ repoff) {
    __shared__ int sb[128];
    const int tid = threadIdx.x;
    const int bid = blockIdx.x;
    if (tid < 128) sb[tid] = (tid < SCAN_NB) ? bsums[tid] : 0;
    __syncthreads();
    for (int off = 1; off < 128; off <<= 1) {
        int add = (tid >= off && tid < 128) ? sb[tid - off] : 0;
        __syncthreads();
        if (tid < 128) sb[tid] += add;
        __syncthreads();
    }
    const int bo = (bid == 0) ? 0 : sb[bid - 1];   // exclusive block offset
    const int n = bid * SCAN_BS + tid;
    if (n < N_NODES) {
        int base = incl[n] - degsum[n] + bo;
        int c0 = deg_rep[n];
        int c1 = deg_rep[N_NODES + n];
        int c2 = deg_rep[2 * N_NODES + n];
        repoff[n] = base;
        repoff[N_NODES + n] = base + c0;
        repoff[2 * N_NODES + n] = base + c0 + c1;
        repoff[3 * N_NODES + n] = base + c0 + c1 + c2;
    }
}

// ---------------- CSR scatter: atomic-free, ushort payload ----------------
__global__ __launch_bounds__(256) void k_scatter(const int* __restrict__ ei,
                                                 const unsigned short* __restrict__ rank,
                                                 const int* __restrict__ repoff,
                                                 unsigned short* __restrict__ csr_col) {
    int e = blockIdx.x * 256 + threadIdx.x;
    if (e < N_EDGES) {
        int r = ei[e];
        int pos = repoff[(e & 3) * N_NODES + r] + rank[e];
        csr_col[pos] = (unsigned short)ei[N_EDGES + e];
    }
}

// ---------------- per-row segment softmax + SpMM: ONE WAVE PER ROW ----------------
// 128 threads = 2 waves = 2 rows. Lane l: edge slot l>>5, feature block j=l&31
// (features 8j..8j+7, head j>>3). Per iter a wave consumes 2 edges:
// one 16B f16x8 gather + 8 v_fma_mix per lane. No barriers (wave-private LDS).
__global__ __launch_bounds__(128) void k_agg(const unsigned short* __restrict__ csr_col,
                                             const int* __restrict__ offs,
                                             const int* __restrict__ deg,
                                             const float* __restrict__ al,
                                             const float* __restrict__ ar,
                                             const _Float16* __restrict__ h16,
                                             float* __restrict__ out) {
    __shared__ float s_w[2][64][4];   // [wave][edge][head]
    __shared__ int   s_c[2][64];
    const int t = threadIdx.x;
    const int w = t >> 6;
    const int l = t & 63;
    const int r = blockIdx.x * 2 + w;     // 25000 blocks x 2
    const int eslot = l >> 5;
    const int j = l & 31;
    const int hd = j >> 3;
    const int dg = deg[r];
    const int start = offs[r];

    const float4 alv = *(const float4*)&al[r * NHEAD];
    const float4* __restrict__ ar4 = (const float4*)ar;
    const f16x8* __restrict__ h8 = (const f16x8*)h16;

    float acc[8];
#pragma unroll
    for (int k = 0; k < 8; ++k) acc[k] = 0.f;
    float4 ps = make_float4(0.f, 0.f, 0.f, 0.f);

    for (int c0 = 0; c0 < dg; c0 += 64) {
        const int n = min(64, dg - c0);
        if (l < n) {
            int c = csr_col[start + c0 + l];
            s_c[w][l] = c;
            float4 arv = ar4[c];
            float e0 = alv.x + arv.x; e0 = (e0 >= 0.f) ? e0 : LRELU_ALPHA * e0;
            float e1 = alv.y + arv.y; e1 = (e1 >= 0.f) ? e1 : LRELU_ALPHA * e1;
            float e2 = alv.z + arv.z; e2 = (e2 >= 0.f) ? e2 : LRELU_ALPHA * e2;
            float e3 = alv.w + arv.w; e3 = (e3 >= 0.f) ? e3 : LRELU_ALPHA * e3;
            float4 wv;
            wv.x = __expf(fminf(e0, 80.f));
            wv.y = __expf(fminf(e1, 80.f));
            wv.z = __expf(fminf(e2, 80.f));
            wv.w = __expf(fminf(e3, 80.f));
            *(float4*)&s_w[w][l][0] = wv;
            ps.x += wv.x; ps.y += wv.y; ps.z += wv.z; ps.w += wv.w;
        }
        // wave-internal LDS write->read: lgkmcnt dependency suffices, no barrier.
        const int np = (n + 1) >> 1;
#pragma unroll 4
        for (int p = 0; p < np; ++p) {
            int i0 = 2 * p + eslot;
            bool v = (i0 < n);
            int c = v ? s_c[w][i0] : s_c[w][0];
            float wt = v ? s_w[w][i0][hd] : 0.f;
            f16x8 hv = h8[(unsigned)((c << 5) | j)];   // 16B coalesced gather
#pragma unroll
            for (int k = 0; k < 8; ++k)
                acc[k] += (float)hv[k] * wt;           // v_fma_mix_f32
        }
    }

    // combine the two edge slots
#pragma unroll
    for (int k = 0; k < 8; ++k) acc[k] += __shfl_xor(acc[k], 32);

    // wave-reduce denominator (all heads), select this lane's head
#pragma unroll
    for (int s = 1; s <= 32; s <<= 1) {
        ps.x += __shfl_xor(ps.x, s);
        ps.y += __shfl_xor(ps.y, s);
        ps.z += __shfl_xor(ps.z, s);
        ps.w += __shfl_xor(ps.w, s);
    }
    float den = (hd == 0) ? ps.x : (hd == 1) ? ps.y : (hd == 2) ? ps.z : ps.w;
    float inv = (den > 0.f) ? 1.f / den : 0.f;
    if (l < 32) {
        float4 o0 = make_float4(acc[0] * inv, acc[1] * inv, acc[2] * inv, acc[3] * inv);
        float4 o1 = make_float4(acc[4] * inv, acc[5] * inv, acc[6] * inv, acc[7] * inv);
        float4* op = (float4*)&out[((size_t)r << 8) + j * 8];
        op[0] = o0;
        op[1] = o1;
    }
}

extern "C" void kernel_launch(void* const* d_in, const int* in_sizes, int n_in,
                              void* d_out, int out_size, void* d_ws, size_t ws_size,
                              hipStream_t stream) {
    const float* x   = (const float*)d_in[0];
    const int*   ei  = (const int*)d_in[1];
    const float* Wm  = (const float*)d_in[2];
    const float* a_l = (const float*)d_in[3];
    const float* a_r = (const float*)d_in[4];
    float* out = (float*)d_out;

    _Float16* h16 = (_Float16*)d_ws;                              // N*256 f16
    _Float16* Wh  = h16 + (size_t)N_NODES * OUT_C;                // 64K f16
    float* al  = (float*)(Wh + 256 * 256);                        // N*4
    float* ar  = al + (size_t)N_NODES * NHEAD;                    // N*4
    int* deg_rep = (int*)(ar + (size_t)N_NODES * NHEAD);          // 4N
    int* degsum  = deg_rep + 4 * N_NODES;                         // N
    int* incl    = degsum + N_NODES;                              // N
    int* bsums   = incl + N_NODES;                                // 128
    int* repoff  = bsums + 128;                                   // 4N (repoff[0]=offs)
    unsigned short* rank    = (unsigned short*)(repoff + 4 * N_NODES);  // E ushort
    unsigned short* csr_col = rank + N_EDGES;                     // E ushort

    hipMemsetAsync(deg_rep, 0, 4 * N_NODES * sizeof(int), stream);

    k_convw<<<256, 256, 0, stream>>>(Wm, Wh);
    k_gemm_hist<<<GEMM_NB + HIST_NB, 256, 0, stream>>>(x, Wh, a_l, a_r, h16, al, ar,
                                                       ei, deg_rep, rank);
    k_scanA<<<SCAN_NB, SCAN_BS, 0, stream>>>(deg_rep, degsum, incl, bsums);
    k_scanB<<<SCAN_NB, SCAN_BS, 0, stream>>>(deg_rep, degsum, incl, bsums, repoff);
    k_scatter<<<HIST_NB, 256, 0, stream>>>(ei, rank, repoff, csr_col);
    k_agg<<<N_NODES / 2, 128, 0, stream>>>(csr_col, repoff, degsum, al, ar, h16, out);
}